// Round 2
// baseline (156.174 us; speedup 1.0000x reference)
//
#include <hip/hip_runtime.h>

#define NN 10000   // nodes
#define NE 25000   // edges
#define DF 128     // features
#define TB 1024    // build-kernel threads

// ---------------------------------------------------------------------------
// Kernel 1: new_x[e] = ((x[u]+x[v])*0.5 + edge_attr[e]) * 0.5 ; 32 thr/edge
// ---------------------------------------------------------------------------
__global__ void k_newx(const float* __restrict__ x, const float* __restrict__ ea,
                       const int* __restrict__ c0, const int* __restrict__ c1,
                       float* __restrict__ out) {
    int tid = blockIdx.x * blockDim.x + threadIdx.x;
    if (tid >= NE * 32) return;
    int e = tid >> 5, q = tid & 31;
    int u = c0[e], v = c1[e];
    float4 a = ((const float4*)(x + (size_t)u * DF))[q];
    float4 b = ((const float4*)(x + (size_t)v * DF))[q];
    float4 c = ((const float4*)(ea + (size_t)e * DF))[q];
    float4 r;
    r.x = ((a.x + b.x) * 0.5f + c.x) * 0.5f;
    r.y = ((a.y + b.y) * 0.5f + c.y) * 0.5f;
    r.z = ((a.z + b.z) * 0.5f + c.z) * 0.5f;
    r.w = ((a.w + b.w) * 0.5f + c.w) * 0.5f;
    ((float4*)(out + (size_t)e * DF))[q] = r;
}

// ---------------------------------------------------------------------------
// Kernel 2: single-workgroup index pipeline.
// LDS: sEnd[NN] (bucket end offsets) + sEdges[NE] (bucket-sorted edge ids)
//      + sPart[TB] (scan partials) = 40000 + 100000 + 4096 = 144 KB.
// Phases: zero -> count -> scan -> atomic fill -> per-bucket insertion sort
//         -> per-edge lg-degree count -> scan -> write rowStart/bStart/bEdges.
// All determinism-sensitive ordering is restored by the in-LDS sort.
// ---------------------------------------------------------------------------
__global__ __launch_bounds__(TB) void k_build(const int* __restrict__ c0,
                                              const int* __restrict__ c1,
                                              int* __restrict__ gBStart,   // NN+1
                                              int* __restrict__ gBEdges,   // NE
                                              int* __restrict__ gRowStart) // NE+1
{
    __shared__ int sEnd[NN];
    __shared__ int sEdges[NE];
    __shared__ int sPart[TB];
    int t = threadIdx.x;

    // zero counts
    for (int n = t; n < NN; n += TB) sEnd[n] = 0;
    __syncthreads();
    // histogram of c0
    for (int j = t; j < NE; j += TB) atomicAdd(&sEnd[c0[j]], 1);
    __syncthreads();
    // exclusive scan of counts -> start offsets (in place in sEnd)
    const int CB = (NN + TB - 1) / TB;              // bins per thread
    int blo = t * CB; if (blo > NN) blo = NN;
    int bhi = blo + CB; if (bhi > NN) bhi = NN;
    int s = 0;
    for (int n = blo; n < bhi; ++n) s += sEnd[n];
    sPart[t] = s;
    __syncthreads();
    for (int off = 1; off < TB; off <<= 1) {
        int add = (t >= off) ? sPart[t - off] : 0;
        __syncthreads();
        sPart[t] += add;
        __syncthreads();
    }
    int run = (t == 0) ? 0 : sPart[t - 1];
    for (int n = blo; n < bhi; ++n) { int c = sEnd[n]; sEnd[n] = run; run += c; }
    __syncthreads();
    // atomic-cursor fill: sEnd[n] walks start(n) -> end(n)
    for (int j = t; j < NE; j += TB) {
        int p = atomicAdd(&sEnd[c0[j]], 1);
        sEdges[p] = j;
    }
    __syncthreads();
    // now sEnd[n] == end(n) == start(n+1); start(n) = (n==0) ? 0 : sEnd[n-1]
    // sort each bucket ascending (deterministic order, matches nonzero())
    for (int n = t; n < NN; n += TB) {
        int bs = (n == 0) ? 0 : sEnd[n - 1];
        int be = sEnd[n];
        for (int i = bs + 1; i < be; ++i) {
            int key = sEdges[i], j2 = i - 1;
            while (j2 >= bs && sEdges[j2] > key) { sEdges[j2 + 1] = sEdges[j2]; --j2; }
            sEdges[j2 + 1] = key;
        }
    }
    __syncthreads();
    // flush bucket structure to global for k_emit
    for (int n = t; n < NN; n += TB) gBStart[n + 1] = sEnd[n];
    if (t == 0) gBStart[0] = 0;
    for (int p = t; p < NE; p += TB) gBEdges[p] = sEdges[p];
    // per-edge line-graph out-degree, then exclusive scan -> gRowStart
    const int CE = (NE + TB - 1) / TB;              // edges per thread
    int elo = t * CE; if (elo > NE) elo = NE;
    int ehi = elo + CE; if (ehi > NE) ehi = NE;
    int esum = 0;
    for (int i = elo; i < ehi; ++i) {
        int u = c0[i], v = c1[i];
        int bs = (v == 0) ? 0 : sEnd[v - 1];
        int be = sEnd[v];
        for (int p = bs; p < be; ++p)
            if (c1[sEdges[p]] != u) ++esum;
    }
    __syncthreads();
    sPart[t] = esum;
    __syncthreads();
    for (int off = 1; off < TB; off <<= 1) {
        int add = (t >= off) ? sPart[t - off] : 0;
        __syncthreads();
        sPart[t] += add;
        __syncthreads();
    }
    int erun = (t == 0) ? 0 : sPart[t - 1];
    for (int i = elo; i < ehi; ++i) {
        int u = c0[i], v = c1[i];
        int bs = (v == 0) ? 0 : sEnd[v - 1];
        int be = sEnd[v];
        gRowStart[i] = erun;
        for (int p = bs; p < be; ++p)
            if (c1[sEdges[p]] != u) ++erun;
    }
    if (t == TB - 1) gRowStart[NE] = sPart[TB - 1];
}

// ---------------------------------------------------------------------------
// Kernel 3: one wave per edge i. All lg-edges of row i share the same attr
// row new_x[c1[i]] -> load once into regs (64 lanes x float2 = 512B), write
// rows/cols/attr for each match while walking bucket[c1[i]].
// ---------------------------------------------------------------------------
__global__ void k_emit(const float* __restrict__ newx,
                       const int* __restrict__ c0, const int* __restrict__ c1,
                       const int* __restrict__ bStart, const int* __restrict__ bEdges,
                       const int* __restrict__ rowStart,
                       float* __restrict__ outRows, float* __restrict__ outCols,
                       float* __restrict__ outAttr) {
    int gtid = blockIdx.x * blockDim.x + threadIdx.x;
    int i = gtid >> 6, lane = gtid & 63;
    if (i >= NE) return;
    int u = c0[i], v = c1[i];
    float2 val = ((const float2*)(newx + (size_t)v * DF))[lane];
    int bs = bStart[v], be = bStart[v + 1];
    int k = rowStart[i];
    for (int p = bs; p < be; ++p) {
        int j = bEdges[p];
        if (c1[j] != u) {
            if (lane == 0) { outRows[k] = (float)i; outCols[k] = (float)j; }
            ((float2*)(outAttr + (size_t)k * DF))[lane] = val;
            ++k;
        }
    }
}

// ---------------------------------------------------------------------------

extern "C" void kernel_launch(void* const* d_in, const int* in_sizes, int n_in,
                              void* d_out, int out_size, void* d_ws, size_t ws_size,
                              hipStream_t stream) {
    const float* x  = (const float*)d_in[0];
    const float* ea = (const float*)d_in[1];
    const int*   ei = (const int*)d_in[2];
    const int* c0 = ei;        // edge_index[0]
    const int* c1 = ei + NE;   // edge_index[1]

    float* out = (float*)d_out;
    int E_lg = (out_size - NE * DF) / (DF + 2);
    if (E_lg < 0) E_lg = 0;

    float* out_newx = out;                      // NE*DF
    float* out_rows = out + (size_t)NE * DF;    // E_lg
    float* out_cols = out_rows + E_lg;          // E_lg
    float* out_attr = out_cols + E_lg;          // E_lg*DF

    int* ws       = (int*)d_ws;
    int* bStart   = ws;                         // NN+1
    int* bEdges   = bStart + NN + 1;            // NE
    int* rowStart = bEdges + NE;                // NE+1

    k_build<<<1, TB, 0, stream>>>(c0, c1, bStart, bEdges, rowStart);
    k_newx<<<(NE * 32 + 255) / 256, 256, 0, stream>>>(x, ea, c0, c1, out_newx);
    k_emit<<<(NE * 64 + 255) / 256, 256, 0, stream>>>(out_newx, c0, c1, bStart, bEdges,
                                                      rowStart, out_rows, out_cols, out_attr);
}

// Round 3
// 83.063 us; speedup vs baseline: 1.8802x; 1.8802x over previous
//
#include <hip/hip_runtime.h>

#define NN 10000   // nodes
#define NE 25000   // edges
#define DF 128     // features

// ---------------------------------------------------------------------------
// K1: new_x[e] = ((x[u]+x[v])*0.5 + edge_attr[e])*0.5  (32 thr/edge, float4)
//     + zero the node-count array (first NN threads).
// ---------------------------------------------------------------------------
__global__ void k_newx_zero(const float* __restrict__ x, const float* __restrict__ ea,
                            const int* __restrict__ c0, const int* __restrict__ c1,
                            float* __restrict__ out, int* __restrict__ cntNode) {
    int tid = blockIdx.x * blockDim.x + threadIdx.x;
    if (tid < NN) cntNode[tid] = 0;
    if (tid >= NE * 32) return;
    int e = tid >> 5, q = tid & 31;
    int u = c0[e], v = c1[e];
    float4 a = ((const float4*)(x + (size_t)u * DF))[q];
    float4 b = ((const float4*)(x + (size_t)v * DF))[q];
    float4 c = ((const float4*)(ea + (size_t)e * DF))[q];
    float4 r;
    r.x = ((a.x + b.x) * 0.5f + c.x) * 0.5f;
    r.y = ((a.y + b.y) * 0.5f + c.y) * 0.5f;
    r.z = ((a.z + b.z) * 0.5f + c.z) * 0.5f;
    r.w = ((a.w + b.w) * 0.5f + c.w) * 0.5f;
    ((float4*)(out + (size_t)e * DF))[q] = r;
}

// K2: histogram of c0
__global__ void k_count(const int* __restrict__ c0, int* __restrict__ cntNode) {
    int j = blockIdx.x * blockDim.x + threadIdx.x;
    if (j < NE) atomicAdd(&cntNode[c0[j]], 1);
}

// K3/K6: single-WG exclusive scan: out[0..n], out[n]=total; optionally also
// write cursor[i]=out[i] (for the atomic bucket fill).
__global__ __launch_bounds__(1024) void k_scan_excl(const int* __restrict__ in,
                                                    int* __restrict__ out,
                                                    int* __restrict__ cursor, int n) {
    __shared__ int part[1024];
    int t = threadIdx.x;
    int C = (n + 1023) >> 10;
    int lo = t * C; if (lo > n) lo = n;
    int hi = lo + C; if (hi > n) hi = n;
    int s = 0;
    for (int i = lo; i < hi; ++i) s += in[i];
    part[t] = s;
    __syncthreads();
    for (int off = 1; off < 1024; off <<= 1) {
        int add = (t >= off) ? part[t - off] : 0;
        __syncthreads();
        part[t] += add;
        __syncthreads();
    }
    int run = (t == 0) ? 0 : part[t - 1];
    for (int i = lo; i < hi; ++i) {
        out[i] = run;
        if (cursor) cursor[i] = run;
        run += in[i];
    }
    if (t == 0) out[n] = part[1023];
}

// K4: atomic-cursor bucket fill (order within bucket arbitrary; fixed in K7)
__global__ void k_fill(const int* __restrict__ c0, int* __restrict__ cursor,
                       int* __restrict__ bEdges) {
    int j = blockIdx.x * blockDim.x + threadIdx.x;
    if (j >= NE) return;
    int p = atomicAdd(&cursor[c0[j]], 1);
    bEdges[p] = j;
}

// K5: per-edge line-graph out-degree (order-independent)
__global__ void k_cnt_edge(const int* __restrict__ c0, const int* __restrict__ c1,
                           const int* __restrict__ bStart, const int* __restrict__ bEdges,
                           int* __restrict__ cntEdge) {
    int i = blockIdx.x * blockDim.x + threadIdx.x;
    if (i >= NE) return;
    int u = c0[i], v = c1[i];
    int s = bStart[v], e = bStart[v + 1], c = 0;
    for (int p = s; p < e; ++p)
        if (c1[bEdges[p]] != u) ++c;
    cntEdge[i] = c;
}

// K7: one wave per edge i.
//  - attr rows for row i are `cnt` identical copies of new_x[c1[i]] -> order
//    within the segment is irrelevant; write cnt copies (float2/lane).
//  - rows/cols need ascending-j order: compute each match's rank-by-value
//    within its bucket (buckets are tiny), lanes write in parallel.
__global__ void k_emit(const float* __restrict__ newx,
                       const int* __restrict__ c0, const int* __restrict__ c1,
                       const int* __restrict__ bStart, const int* __restrict__ bEdges,
                       const int* __restrict__ rowStart,
                       float* __restrict__ outRows, float* __restrict__ outCols,
                       float* __restrict__ outAttr) {
    int gtid = blockIdx.x * blockDim.x + threadIdx.x;
    int i = gtid >> 6, lane = gtid & 63;
    if (i >= NE) return;
    int u = c0[i], v = c1[i];
    int base = rowStart[i];
    int cnt  = rowStart[i + 1] - base;
    if (cnt == 0) return;
    // attr copies
    float2 val = ((const float2*)(newx + (size_t)v * DF))[lane];
    for (int t = 0; t < cnt; ++t)
        ((float2*)(outAttr + (size_t)(base + t) * DF))[lane] = val;
    // rows/cols with rank-by-value (generic, handles any bucket size)
    int bs = bStart[v], be = bStart[v + 1], B = be - bs;
    for (int p = lane; p < B; p += 64) {
        int jp = bEdges[bs + p];
        if (c1[jp] == u) continue;
        int rank = 0;
        for (int q = 0; q < B; ++q) {
            int jq = bEdges[bs + q];
            rank += (c1[jq] != u && jq < jp) ? 1 : 0;
        }
        outRows[base + rank] = (float)i;
        outCols[base + rank] = (float)jp;
    }
}

// ---------------------------------------------------------------------------

extern "C" void kernel_launch(void* const* d_in, const int* in_sizes, int n_in,
                              void* d_out, int out_size, void* d_ws, size_t ws_size,
                              hipStream_t stream) {
    const float* x  = (const float*)d_in[0];
    const float* ea = (const float*)d_in[1];
    const int*   ei = (const int*)d_in[2];
    const int* c0 = ei;        // edge_index[0]
    const int* c1 = ei + NE;   // edge_index[1]

    float* out = (float*)d_out;
    int E_lg = (out_size - NE * DF) / (DF + 2);
    if (E_lg < 0) E_lg = 0;

    float* out_newx = out;                      // NE*DF
    float* out_rows = out + (size_t)NE * DF;    // E_lg
    float* out_cols = out_rows + E_lg;          // E_lg
    float* out_attr = out_cols + E_lg;          // E_lg*DF

    int* ws       = (int*)d_ws;
    int* cntNode  = ws;                         // NN
    int* bStart   = cntNode + NN;               // NN+1
    int* cursor   = bStart + NN + 1;            // NN
    int* bEdges   = cursor + NN;                // NE
    int* cntEdge  = bEdges + NE;                // NE
    int* rowStart = cntEdge + NE;               // NE+1

    k_newx_zero<<<(NE * 32 + 255) / 256, 256, 0, stream>>>(x, ea, c0, c1, out_newx, cntNode);
    k_count<<<(NE + 255) / 256, 256, 0, stream>>>(c0, cntNode);
    k_scan_excl<<<1, 1024, 0, stream>>>(cntNode, bStart, cursor, NN);
    k_fill<<<(NE + 255) / 256, 256, 0, stream>>>(c0, cursor, bEdges);
    k_cnt_edge<<<(NE + 255) / 256, 256, 0, stream>>>(c0, c1, bStart, bEdges, cntEdge);
    k_scan_excl<<<1, 1024, 0, stream>>>(cntEdge, rowStart, nullptr, NE);
    k_emit<<<(NE * 64 + 255) / 256, 256, 0, stream>>>(out_newx, c0, c1, bStart, bEdges,
                                                      rowStart, out_rows, out_cols, out_attr);
}